// Round 9
// baseline (674.798 us; speedup 1.0000x reference)
//
#include <hip/hip_runtime.h>

#define NN 100000
#define NE 1600000

constexpr int NBUC = 196;       // bucket = dst >> 9 (512 nodes/bucket)
constexpr int BIN_CHUNK = 4096;
constexpr int NB_BIN = (NE + BIN_CHUNK - 1) / BIN_CHUNK;  // 391

typedef __attribute__((ext_vector_type(8))) short s16x8;
typedef __attribute__((ext_vector_type(4))) float f32x4;
typedef __attribute__((ext_vector_type(2))) float f32x2;

__device__ inline unsigned short f2bf(float f) {  // RNE fp32 -> bf16 bits
    unsigned int u = __float_as_uint(f);
    return (unsigned short)((u + 0x7fffu + ((u >> 16) & 1u)) >> 16);
}
__device__ inline float bf_lo(unsigned int pk) { return __uint_as_float(pk << 16); }
__device__ inline float bf_hi(unsigned int pk) { return __uint_as_float(pk & 0xffff0000u); }

__global__ void zero_u32(unsigned int* p, int n) {
    int i = blockIdx.x * blockDim.x + threadIdx.x;
    if (i < n) p[i] = 0u;
}

// Histogram of dst buckets (LDS-combined, 196 global atomics per block).
__global__ __launch_bounds__(256) void bucket_count(const int* __restrict__ dst,
                                                    int* __restrict__ bcount) {
    __shared__ int hist[NBUC];
    int t = threadIdx.x;
    for (int b = t; b < NBUC; b += 256) hist[b] = 0;
    __syncthreads();
    int beg = blockIdx.x * BIN_CHUNK;
    int end = min(beg + BIN_CHUNK, NE);
    for (int i = beg + t; i < end; i += 256) atomicAdd(&hist[dst[i] >> 9], 1);
    __syncthreads();
    for (int b = t; b < NBUC; b += 256)
        if (hist[b]) atomicAdd(&bcount[b], hist[b]);
}

// Serial 196-entry exclusive scan; writes bucket bases + bin cursors.
__global__ void bucket_scan(const int* __restrict__ bcount, int* __restrict__ bbase,
                            int* __restrict__ bucket_cursor, int* __restrict__ offsets) {
    if (threadIdx.x == 0) {
        int run = 0;
        for (int b = 0; b < NBUC; ++b) {
            bbase[b] = run;
            bucket_cursor[b] = run;
            run += bcount[b];
        }
        bbase[NBUC] = NE;
        offsets[NN] = NE;
    }
}

// Bucket-major packed intermediate: (local_dst9 << 17) | src17. Per-block LDS
// histogram, per-bucket chunk reservation, contiguous 4B writes.
__global__ __launch_bounds__(256) void bin_edges(const int* __restrict__ src,
                                                 const int* __restrict__ dst,
                                                 int* __restrict__ bucket_cursor,
                                                 unsigned int* __restrict__ binned) {
    __shared__ int hist[NBUC];
    __shared__ int base[NBUC];
    int t = threadIdx.x;
    for (int b = t; b < NBUC; b += 256) hist[b] = 0;
    __syncthreads();
    int beg = blockIdx.x * BIN_CHUNK;
    int end = min(beg + BIN_CHUNK, NE);
    for (int i = beg + t; i < end; i += 256) atomicAdd(&hist[dst[i] >> 9], 1);
    __syncthreads();
    for (int b = t; b < NBUC; b += 256) {
        base[b] = hist[b] ? atomicAdd(&bucket_cursor[b], hist[b]) : 0;
        hist[b] = 0;
    }
    __syncthreads();
    for (int i = beg + t; i < end; i += 256) {
        int d = dst[i];
        int bk = d >> 9;
        int loc = atomicAdd(&hist[bk], 1);
        binned[base[bk] + loc] = ((unsigned)(d & 511) << 17) | (unsigned)src[i];
    }
}

// One block per bucket: LDS counting sort over the bucket's 512 nodes.
// Emits offsets + csr_src/csr_dst with sequential (in-bucket) global writes.
__global__ __launch_bounds__(256) void bucket_sort(const unsigned int* __restrict__ binned,
                                                   const int* __restrict__ bbase,
                                                   int* __restrict__ offsets,
                                                   int* __restrict__ csr_src,
                                                   int* __restrict__ csr_dst) {
    __shared__ int deg[512];
    __shared__ int loc[512];
    __shared__ int s2[256];
    int t = threadIdx.x;
    int b = blockIdx.x;
    int beg = bbase[b], end = bbase[b + 1];
    int nbase = b << 9;
    deg[t] = 0;
    deg[t + 256] = 0;
    __syncthreads();
    for (int i = beg + t; i < end; i += 256) atomicAdd(&deg[binned[i] >> 17], 1);
    __syncthreads();
    int pairsum = deg[2 * t] + deg[2 * t + 1];
    s2[t] = pairsum;
    __syncthreads();
    for (int off = 1; off < 256; off <<= 1) {
        int v = (t >= off) ? s2[t - off] : 0;
        __syncthreads();
        s2[t] += v;
        __syncthreads();
    }
    int ex = s2[t] - pairsum;  // exclusive pair base
    loc[2 * t] = ex;
    loc[2 * t + 1] = ex + deg[2 * t];
    __syncthreads();
    for (int i = t; i < 512; i += 256) {
        int node = nbase + i;
        if (node < NN) offsets[node] = beg + loc[i];
    }
    __syncthreads();
    for (int i = beg + t; i < end; i += 256) {
        unsigned int v = binned[i];
        int dl = v >> 17;
        int pos = atomicAdd(&loc[dl], 1);
        csr_src[beg + pos] = (int)(v & 0x1FFFFu);
        csr_dst[beg + pos] = nbase + dl;
    }
}

// Transpose + fp32->bf16 all weights once per launch.
// Wtcat[256][128]: cols(oc) 0..127 = W0, 128..191 = skip0, 192..255 = projW.
__global__ void prep_weights(const float* __restrict__ W0, const float* __restrict__ skip0,
                             const float* __restrict__ projW, const float* __restrict__ W1,
                             const float* __restrict__ W2, unsigned short* __restrict__ Wtcat,
                             unsigned short* __restrict__ Wt1, unsigned short* __restrict__ Wt2) {
    int i = blockIdx.x * 256 + threadIdx.x;
    if (i < 32768) {
        int oc = i >> 7, k = i & 127;
        float v;
        if (oc < 128) v = W0[k * 128 + oc];
        else if (oc < 192) v = skip0[k * 64 + (oc - 128)];
        else v = projW[k * 64 + (oc - 192)];
        Wtcat[oc * 128 + k] = f2bf(v);
    } else if (i < 40960) {
        int j = i - 32768, oc = j >> 6, k = j & 63;
        Wt1[oc * 64 + k] = f2bf(W1[k * 128 + oc]);
    } else if (i < 49152) {
        int j = i - 40960, oc = j >> 6, k = j & 63;
        Wt2[oc * 64 + k] = f2bf(W2[k * 128 + oc]);
    }
}

// Layer-0 single-pass GEMM: block = 64 rows x 256 cols (h|skip|proj), 4 waves.
// X fp32 read ONCE; B staged in two 64-K chunks. Outputs: packed fp8 h,
// fp32 skipx, fp32 jkproj(+bias), packed bf16 scores.
__global__ __launch_bounds__(256) void gemm_l0(
    const float* __restrict__ X, const unsigned short* __restrict__ Wt,
    unsigned int* __restrict__ Hq32, float* __restrict__ skipx, float* __restrict__ jkproj,
    const float* __restrict__ projb, const float* __restrict__ as_v,
    const float* __restrict__ ad_v, unsigned int* __restrict__ e_srcpk,
    unsigned int* __restrict__ e_dstpk) {
    __shared__ unsigned short As[64 * 136];  // 64 rows x (128+8)
    __shared__ unsigned short Bs[256 * 72];  // 256 cols x (64+8) per K-chunk
    int t = threadIdx.x;
    int rbase = blockIdx.x * 64;

    for (int i = t; i < 64 * 32; i += 256) {
        int r = i >> 5;
        int kq = (i & 31) * 4;
        int gr = rbase + r;
        float4 v = make_float4(0.f, 0.f, 0.f, 0.f);
        if (gr < NN) v = *(const float4*)&X[(size_t)gr * 128 + kq];
        uint2 u;
        u.x = (unsigned int)f2bf(v.x) | ((unsigned int)f2bf(v.y) << 16);
        u.y = (unsigned int)f2bf(v.z) | ((unsigned int)f2bf(v.w) << 16);
        *(uint2*)&As[r * 136 + kq] = u;
    }

    int lane = t & 63, wv = t >> 6;
    int lr = lane & 15, quad = lane >> 4;
    int arow = wv * 16 + lr;
    f32x4 acc[16];
#pragma unroll
    for (int c = 0; c < 16; ++c) acc[c] = (f32x4)(0.f);

#pragma unroll
    for (int kc = 0; kc < 128; kc += 64) {
        __syncthreads();
        for (int i = t; i < 256 * 8; i += 256) {
            int oc = i >> 3;
            int k8 = (i & 7) * 8;
            *(uint4*)&Bs[oc * 72 + k8] = *(const uint4*)&Wt[(size_t)oc * 128 + kc + k8];
        }
        __syncthreads();
#pragma unroll
        for (int k0 = 0; k0 < 64; k0 += 32) {
            s16x8 a = *(const s16x8*)&As[arow * 136 + kc + k0 + quad * 8];
#pragma unroll
            for (int ct = 0; ct < 16; ++ct) {
                s16x8 b = *(const s16x8*)&Bs[(ct * 16 + lr) * 72 + k0 + quad * 8];
                acc[ct] = __builtin_amdgcn_mfma_f32_16x16x32_bf16(a, b, acc[ct], 0, 0, 0);
            }
        }
    }

#pragma unroll
    for (int reg = 0; reg < 4; ++reg) {
        int row = rbase + wv * 16 + quad * 4 + reg;
        bool ok = row < NN;
        // h (cols 0..127 = W0): pack fp8 pairs, 2 channels/dword
#pragma unroll
        for (int ct = 0; ct < 4; ++ct) {
            int pk = __builtin_amdgcn_cvt_pk_fp8_f32(acc[ct][reg], acc[ct + 4][reg], 0, false);
            int pn = __shfl_xor(pk, 1, 64);
            if (ok && !(lr & 1))
                Hq32[(size_t)row * 32 + ct * 8 + (lr >> 1)] =
                    (unsigned int)((pk & 0xFFFF) | (pn << 16));
        }
        // scores from fp32 acc
        float s0 = 0.f, s1 = 0.f, d0 = 0.f, d1 = 0.f;
#pragma unroll
        for (int ct = 0; ct < 4; ++ct) {
            int c = ct * 16 + lr;
            float hlo = acc[ct][reg], hhi = acc[ct + 4][reg];
            s0 += hlo * as_v[c];
            s1 += hhi * as_v[64 + c];
            d0 += hlo * ad_v[c];
            d1 += hhi * ad_v[64 + c];
        }
#pragma unroll
        for (int off = 1; off < 16; off <<= 1) {
            s0 += __shfl_xor(s0, off, 64);
            s1 += __shfl_xor(s1, off, 64);
            d0 += __shfl_xor(d0, off, 64);
            d1 += __shfl_xor(d1, off, 64);
        }
        if (lr == 0 && ok) {
            e_srcpk[row] = (unsigned int)f2bf(s0) | ((unsigned int)f2bf(s1) << 16);
            e_dstpk[row] = (unsigned int)f2bf(d0) | ((unsigned int)f2bf(d1) << 16);
        }
        if (ok) {
#pragma unroll
            for (int ct = 8; ct < 12; ++ct)
                skipx[(size_t)row * 64 + (ct - 8) * 16 + lr] = acc[ct][reg];
#pragma unroll
            for (int ct = 12; ct < 16; ++ct) {
                int c = (ct - 12) * 16 + lr;
                jkproj[(size_t)row * 64 + c] = acc[ct][reg] + projb[c];
            }
        }
    }
}

// Layers 1/2 MFMA GEMM: block = 64 rows x 128 cols, 4 waves. X fp32 staged to
// LDS bf16 with BN+lrelu applied on the fly. Outputs packed fp8 h + scores.
__global__ __launch_bounds__(256) void gemm_mfma64(
    const float* __restrict__ X, const unsigned short* __restrict__ Wt,
    unsigned int* __restrict__ Hq32, const float* __restrict__ bnsc,
    const float* __restrict__ as_v, const float* __restrict__ ad_v,
    unsigned int* __restrict__ e_srcpk, unsigned int* __restrict__ e_dstpk) {
    constexpr int KP = 72;
    __shared__ unsigned short As[64 * KP];
    __shared__ unsigned short Bs[128 * KP];
    int t = threadIdx.x;
    int rbase = blockIdx.x * 64;

    for (int i = t; i < 64 * 16; i += 256) {
        int r = i >> 4;
        int kq = (i & 15) * 4;
        int gr = rbase + r;
        float4 v = make_float4(0.f, 0.f, 0.f, 0.f);
        if (gr < NN) {
            v = *(const float4*)&X[(size_t)gr * 64 + kq];
            float* vc = (float*)&v;
#pragma unroll
            for (int c = 0; c < 4; ++c) {
                float val = vc[c] * bnsc[kq + c] + bnsc[64 + kq + c];
                vc[c] = val >= 0.f ? val : 0.01f * val;
            }
        }
        uint2 u;
        u.x = (unsigned int)f2bf(v.x) | ((unsigned int)f2bf(v.y) << 16);
        u.y = (unsigned int)f2bf(v.z) | ((unsigned int)f2bf(v.w) << 16);
        *(uint2*)&As[r * KP + kq] = u;
    }
    for (int i = t; i < 128 * 8; i += 256) {
        int oc = i >> 3;
        int k8 = (i & 7) * 8;
        *(uint4*)&Bs[oc * KP + k8] = *(const uint4*)&Wt[(size_t)oc * 64 + k8];
    }
    __syncthreads();

    int lane = t & 63, wv = t >> 6;
    int lr = lane & 15, quad = lane >> 4;
    int arow = wv * 16 + lr;
    f32x4 acc[8];
#pragma unroll
    for (int c = 0; c < 8; ++c) acc[c] = (f32x4)(0.f);
#pragma unroll
    for (int k0 = 0; k0 < 64; k0 += 32) {
        s16x8 a = *(const s16x8*)&As[arow * KP + k0 + quad * 8];
#pragma unroll
        for (int ct = 0; ct < 8; ++ct) {
            s16x8 b = *(const s16x8*)&Bs[(ct * 16 + lr) * KP + k0 + quad * 8];
            acc[ct] = __builtin_amdgcn_mfma_f32_16x16x32_bf16(a, b, acc[ct], 0, 0, 0);
        }
    }

#pragma unroll
    for (int reg = 0; reg < 4; ++reg) {
        int row = rbase + wv * 16 + quad * 4 + reg;
        bool ok = row < NN;
#pragma unroll
        for (int ct = 0; ct < 4; ++ct) {
            int pk = __builtin_amdgcn_cvt_pk_fp8_f32(acc[ct][reg], acc[ct + 4][reg], 0, false);
            int pn = __shfl_xor(pk, 1, 64);
            if (ok && !(lr & 1))
                Hq32[(size_t)row * 32 + ct * 8 + (lr >> 1)] =
                    (unsigned int)((pk & 0xFFFF) | (pn << 16));
        }
        float s0 = 0.f, s1 = 0.f, d0 = 0.f, d1 = 0.f;
#pragma unroll
        for (int ct = 0; ct < 4; ++ct) {
            int c = ct * 16 + lr;
            float hlo = acc[ct][reg], hhi = acc[ct + 4][reg];
            s0 += hlo * as_v[c];
            s1 += hhi * as_v[64 + c];
            d0 += hlo * ad_v[c];
            d1 += hhi * ad_v[64 + c];
        }
#pragma unroll
        for (int off = 1; off < 16; off <<= 1) {
            s0 += __shfl_xor(s0, off, 64);
            s1 += __shfl_xor(s1, off, 64);
            d0 += __shfl_xor(d0, off, 64);
            d1 += __shfl_xor(d1, off, 64);
        }
        if (lr == 0 && ok) {
            e_srcpk[row] = (unsigned int)f2bf(s0) | ((unsigned int)f2bf(s1) << 16);
            e_dstpk[row] = (unsigned int)f2bf(d0) | ((unsigned int)f2bf(d1) << 16);
        }
    }
}

// Per-edge records in CSR order: erec[i] = {src, packed bf16x2 weight}.
__global__ void edge_w(const int* __restrict__ csr_src, const int* __restrict__ csr_dst,
                       const unsigned int* __restrict__ e_srcpk,
                       const unsigned int* __restrict__ e_dstpk,
                       uint2* __restrict__ erec) {
    int i = blockIdx.x * blockDim.x + threadIdx.x;
    if (i >= NE) return;
    int s = csr_src[i];
    unsigned int q = e_srcpk[s];
    unsigned int r = e_dstpk[csr_dst[i]];
    float a0 = bf_lo(q) + bf_lo(r);
    float a1 = bf_hi(q) + bf_hi(r);
    a0 = a0 >= 0.f ? a0 : 0.2f * a0;
    a1 = a1 >= 0.f ? a1 : 0.2f * a1;
    unsigned int w = (unsigned int)f2bf(__expf(a0)) | ((unsigned int)f2bf(__expf(a1)) << 16);
    erec[i] = make_uint2((unsigned)s, w);
}

// One wave per destination node, half-wave edge split. Packed f32x2 math
// (v_pk_fma_f32) + one uint4 load per 4 edges (prefix-peeled so j is even).
// Per 4 edges: 3 VMEM + ~22 wave-level VALU.
__global__ __launch_bounds__(256) void aggregate(
    const int* __restrict__ offsets, const uint2* __restrict__ erec,
    const unsigned int* __restrict__ Hq32, const float* __restrict__ skipsrc,
    const float* __restrict__ bnsc, const float* __restrict__ bias,
    float* __restrict__ hraw) {
    int wave = threadIdx.x >> 6;
    int lane = threadIdx.x & 63;
    int n = blockIdx.x * 4 + wave;
    if (n >= NN) return;
    int half = lane >> 5;   // which edge of a pair
    int cp = lane & 31;     // channel pair
    int beg = offsets[n], end = offsets[n + 1];
    f32x2 accE = {0.f, 0.f}, accO = {0.f, 0.f}, den = {0.f, 0.f};
    int j = beg;
    if ((j & 1) && j < end) {  // peel to even j (uint4 alignment)
        if (half == 0) {
            uint2 e = erec[j];
            unsigned int p = Hq32[(size_t)e.x * 32 + cp];
            f32x2 w = {bf_lo(e.y), bf_hi(e.y)};
            accE += w * __builtin_amdgcn_cvt_pk_f32_fp8((int)p, false);
            accO += w * __builtin_amdgcn_cvt_pk_f32_fp8((int)p, true);
            den += w;
        }
        ++j;
    }
    const uint4* erec4 = (const uint4*)erec;
    for (; j + 3 < end; j += 4) {
        uint4 e2 = erec4[(j >> 1) + half];  // 2 edges for this half
        unsigned int pA = Hq32[(size_t)e2.x * 32 + cp];
        unsigned int pB = Hq32[(size_t)e2.z * 32 + cp];
        f32x2 wA = {bf_lo(e2.y), bf_hi(e2.y)};
        f32x2 wB = {bf_lo(e2.w), bf_hi(e2.w)};
        accE += wA * __builtin_amdgcn_cvt_pk_f32_fp8((int)pA, false);
        accO += wA * __builtin_amdgcn_cvt_pk_f32_fp8((int)pA, true);
        accE += wB * __builtin_amdgcn_cvt_pk_f32_fp8((int)pB, false);
        accO += wB * __builtin_amdgcn_cvt_pk_f32_fp8((int)pB, true);
        den += wA + wB;
    }
    if (j + 1 < end) {  // pair tail
        uint2 e = erec[j + half];
        unsigned int p = Hq32[(size_t)e.x * 32 + cp];
        f32x2 w = {bf_lo(e.y), bf_hi(e.y)};
        accE += w * __builtin_amdgcn_cvt_pk_f32_fp8((int)p, false);
        accO += w * __builtin_amdgcn_cvt_pk_f32_fp8((int)p, true);
        den += w;
        j += 2;
    }
    if (j < end && half == 0) {  // single tail
        uint2 e = erec[j];
        unsigned int p = Hq32[(size_t)e.x * 32 + cp];
        f32x2 w = {bf_lo(e.y), bf_hi(e.y)};
        accE += w * __builtin_amdgcn_cvt_pk_f32_fp8((int)p, false);
        accO += w * __builtin_amdgcn_cvt_pk_f32_fp8((int)p, true);
        den += w;
    }
#pragma unroll
    for (int c = 0; c < 2; ++c) {
        accE[c] += __shfl_xor(accE[c], 32, 64);
        accO[c] += __shfl_xor(accO[c], 32, 64);
        den[c] += __shfl_xor(den[c], 32, 64);
    }
    if (half == 0) {
        float2 sv = *(const float2*)&skipsrc[(size_t)n * 64 + 2 * cp];
        if (bnsc) {  // identity skip from previous layer's pre-BN buffer
            sv.x = sv.x * bnsc[2 * cp] + bnsc[64 + 2 * cp];
            sv.y = sv.y * bnsc[2 * cp + 1] + bnsc[64 + 2 * cp + 1];
            sv.x = sv.x >= 0.f ? sv.x : 0.01f * sv.x;
            sv.y = sv.y >= 0.f ? sv.y : 0.01f * sv.y;
        }
        float2 bi = *(const float2*)&bias[2 * cp];
        float id0 = 1.f / (den[0] + 1e-16f), id1 = 1.f / (den[1] + 1e-16f);
        float2 o;
        o.x = 0.5f * (accE[0] * id0 + accE[1] * id1) + bi.x + sv.x;
        o.y = 0.5f * (accO[0] * id0 + accO[1] * id1) + bi.y + sv.y;
        *(float2*)&hraw[(size_t)n * 64 + 2 * cp] = o;
    }
}

__global__ void bn_stats(const float* __restrict__ x, float* __restrict__ sums) {
    __shared__ float ls[256], ls2[256];
    int t = threadIdx.x;
    int c = t & 63, q = t >> 6;
    float s = 0.f, s2 = 0.f;
    int rbeg = blockIdx.x * 512;
    for (int r = rbeg + q; r < rbeg + 512; r += 4) {
        if (r < NN) {
            float v = x[(size_t)r * 64 + c];
            s += v;
            s2 += v * v;
        }
    }
    ls[t] = s;
    ls2[t] = s2;
    __syncthreads();
    if (t < 64) {
        s = ls[t] + ls[t + 64] + ls[t + 128] + ls[t + 192];
        s2 = ls2[t] + ls2[t + 64] + ls2[t + 128] + ls2[t + 192];
        atomicAdd(&sums[c], s);
        atomicAdd(&sums[64 + c], s2);
    }
}

__global__ void bn_final(const float* __restrict__ sums, const float* __restrict__ g,
                         const float* __restrict__ be, float* __restrict__ sc_sh) {
    int c = threadIdx.x;
    if (c < 64) {
        float mu = sums[c] / (float)NN;
        float var = sums[64 + c] / (float)NN - mu * mu;
        float sc = g[c] * rsqrtf(var + 1e-5f);
        sc_sh[c] = sc;
        sc_sh[64 + c] = be[c] - mu * sc;
    }
}

// JK max over {input proj, lrelu(bn_k(hraw_k))} for k=0,1,2 in one pass.
__global__ void final_out(const float* __restrict__ jkproj, const float* __restrict__ hA,
                          const float* __restrict__ hB, const float* __restrict__ hC,
                          const float* __restrict__ bnAll, float* __restrict__ out) {
    int i = blockIdx.x * blockDim.x + threadIdx.x;
    if (i < NN * 64) {
        int c = i & 63;
        float v0 = hA[i] * bnAll[c] + bnAll[64 + c];
        float v1 = hB[i] * bnAll[128 + c] + bnAll[192 + c];
        float v2 = hC[i] * bnAll[256 + c] + bnAll[320 + c];
        v0 = v0 >= 0.f ? v0 : 0.01f * v0;
        v1 = v1 >= 0.f ? v1 : 0.01f * v1;
        v2 = v2 >= 0.f ? v2 : 0.01f * v2;
        out[i] = fmaxf(fmaxf(jkproj[i], v0), fmaxf(v1, v2));
    }
}

extern "C" void kernel_launch(void* const* d_in, const int* in_sizes, int n_in,
                              void* d_out, int out_size, void* d_ws, size_t ws_size,
                              hipStream_t stream) {
    const float* x = (const float*)d_in[0];
    const int* ei = (const int*)d_in[1];
    const int* e_src_idx = ei;
    const int* e_dst_idx = ei + NE;
    const float* W0 = (const float*)d_in[2];
    const float* as0 = (const float*)d_in[3];
    const float* ad0 = (const float*)d_in[4];
    const float* b0 = (const float*)d_in[5];
    const float* skip0 = (const float*)d_in[6];
    const float* g0 = (const float*)d_in[7];
    const float* be0 = (const float*)d_in[8];
    const float* W1 = (const float*)d_in[9];
    const float* as1 = (const float*)d_in[10];
    const float* ad1 = (const float*)d_in[11];
    const float* b1 = (const float*)d_in[12];
    const float* g1 = (const float*)d_in[13];
    const float* be1 = (const float*)d_in[14];
    const float* W2 = (const float*)d_in[15];
    const float* as2 = (const float*)d_in[16];
    const float* ad2 = (const float*)d_in[17];
    const float* b2 = (const float*)d_in[18];
    const float* g2 = (const float*)d_in[19];
    const float* be2 = (const float*)d_in[20];
    const float* projW = (const float*)d_in[21];
    const float* projb = (const float*)d_in[22];
    float* out = (float*)d_out;

    char* p = (char*)d_ws;
    auto alloc = [&](size_t bytes) {
        char* r = p;
        p += (bytes + 255) & ~(size_t)255;
        return r;
    };
    // bcount (196 ints) + bnsumAll (384 floats) share one zeroed buffer.
    int* zbuf = (int*)alloc((size_t)(196 + 384) * 4);
    int* bcount = zbuf;
    float* bnsumAll = (float*)(zbuf + 196);
    int* bbase = (int*)alloc((size_t)(NBUC + 1) * 4);
    int* bucket_cursor = (int*)alloc((size_t)NBUC * 4);
    int* offsets = (int*)alloc((size_t)(NN + 1) * 4);
    int* csr_src = (int*)alloc((size_t)NE * 4);
    int* csr_dst = (int*)alloc((size_t)NE * 4);
    uint2* erec = (uint2*)alloc((size_t)NE * 8);
    unsigned int* binned = (unsigned int*)alloc((size_t)NE * 4);
    unsigned int* h_q32 = (unsigned int*)alloc((size_t)NN * 32 * 4);
    unsigned int* e_srcpk = (unsigned int*)alloc((size_t)NN * 4);
    unsigned int* e_dstpk = (unsigned int*)alloc((size_t)NN * 4);
    float* skipx = (float*)alloc((size_t)NN * 64 * 4);
    float* jkproj = (float*)alloc((size_t)NN * 64 * 4);
    float* hrawA = (float*)alloc((size_t)NN * 64 * 4);
    float* hrawB = (float*)alloc((size_t)NN * 64 * 4);
    float* hrawC = (float*)alloc((size_t)NN * 64 * 4);
    unsigned short* Wtcat = (unsigned short*)alloc(256 * 128 * 2);
    unsigned short* Wt1 = (unsigned short*)alloc(128 * 64 * 2);
    unsigned short* Wt2 = (unsigned short*)alloc(128 * 64 * 2);
    float* bnscAll = (float*)alloc(3 * 128 * 4);
    if ((size_t)(p - (char*)d_ws) > ws_size) return;

    // ---- CSR by destination: bucket count -> scan -> bin -> LDS sort ----
    zero_u32<<<3, 256, 0, stream>>>((unsigned int*)zbuf, 196 + 384);
    bucket_count<<<NB_BIN, 256, 0, stream>>>(e_dst_idx, bcount);
    bucket_scan<<<1, 64, 0, stream>>>(bcount, bbase, bucket_cursor, offsets);
    bin_edges<<<NB_BIN, 256, 0, stream>>>(e_src_idx, e_dst_idx, bucket_cursor, binned);
    bucket_sort<<<NBUC, 256, 0, stream>>>(binned, bbase, offsets, csr_src, csr_dst);
    prep_weights<<<192, 256, 0, stream>>>(W0, skip0, projW, W1, W2, Wtcat, Wt1, Wt2);

    int gblocks = (NN + 63) / 64;  // 1563

    // ---- Layer 0 (single-pass GEMM: h+scores+skip+proj) ----
    gemm_l0<<<gblocks, 256, 0, stream>>>(x, Wtcat, h_q32, skipx, jkproj, projb, as0, ad0,
                                         e_srcpk, e_dstpk);
    edge_w<<<(NE + 255) / 256, 256, 0, stream>>>(csr_src, csr_dst, e_srcpk, e_dstpk, erec);
    aggregate<<<(NN + 3) / 4, 256, 0, stream>>>(offsets, erec, h_q32, skipx, nullptr, b0,
                                                hrawA);
    bn_stats<<<(NN + 511) / 512, 256, 0, stream>>>(hrawA, bnsumAll);
    bn_final<<<1, 64, 0, stream>>>(bnsumAll, g0, be0, bnscAll);

    // ---- Layer 1 ----
    gemm_mfma64<<<gblocks, 256, 0, stream>>>(hrawA, Wt1, h_q32, bnscAll, as1, ad1, e_srcpk,
                                             e_dstpk);
    edge_w<<<(NE + 255) / 256, 256, 0, stream>>>(csr_src, csr_dst, e_srcpk, e_dstpk, erec);
    aggregate<<<(NN + 3) / 4, 256, 0, stream>>>(offsets, erec, h_q32, hrawA, bnscAll, b1,
                                                hrawB);
    bn_stats<<<(NN + 511) / 512, 256, 0, stream>>>(hrawB, bnsumAll + 128);
    bn_final<<<1, 64, 0, stream>>>(bnsumAll + 128, g1, be1, bnscAll + 128);

    // ---- Layer 2 ----
    gemm_mfma64<<<gblocks, 256, 0, stream>>>(hrawB, Wt2, h_q32, bnscAll + 128, as2, ad2,
                                             e_srcpk, e_dstpk);
    edge_w<<<(NE + 255) / 256, 256, 0, stream>>>(csr_src, csr_dst, e_srcpk, e_dstpk, erec);
    aggregate<<<(NN + 3) / 4, 256, 0, stream>>>(offsets, erec, h_q32, hrawB, bnscAll + 128,
                                                b2, hrawC);
    bn_stats<<<(NN + 511) / 512, 256, 0, stream>>>(hrawC, bnsumAll + 256);
    bn_final<<<1, 64, 0, stream>>>(bnsumAll + 256, g2, be2, bnscAll + 256);

    final_out<<<(NN * 64 + 255) / 256, 256, 0, stream>>>(jkproj, hrawA, hrawB, hrawC,
                                                         bnscAll, out);
}